// Round 12
// baseline (195.639 us; speedup 1.0000x reference)
//
#include <hip/hip_runtime.h>
#include <math.h>

#define NN 100000
#define NE 1600000
#define BSZ 64                          // dst nodes per bucket
#define NBUCK ((NN + BSZ - 1) / BSZ)    // 1563
#define NBLK 256                        // scatter blocks / hist columns
#define CHUNK ((NE + NBLK - 1) / NBLK)  // 6250 edges per block
#define NH (NBUCK * NBLK)               // 400128 hist entries
#define NSB ((NH + 1023) / 1024)        // 391 scan blocks

typedef unsigned int uint;
typedef unsigned short ushort_t;
typedef float f32x4 __attribute__((ext_vector_type(4)));
typedef short s16x8 __attribute__((ext_vector_type(8)));

union U4S8 { uint4 u; s16x8 s; };

// bf16 helpers (RNE pack, shift-decode)
__device__ inline uint bf16_1(float f) {
  uint u = __float_as_uint(f);
  return (u + 0x7FFFu + ((u >> 16) & 1u)) >> 16;
}
__device__ inline uint bf16_2(float lo, float hi) {
  return bf16_1(lo) | (bf16_1(hi) << 16);
}
__device__ inline float blo(uint u) { return __uint_as_float(u << 16); }
__device__ inline float bhi(uint u) { return __uint_as_float(u & 0xFFFF0000u); }

__device__ inline f32x4 mfma_bf16(uint4 a, uint4 b, f32x4 c) {
  U4S8 ua, ub; ua.u = a; ub.u = b;
  return __builtin_amdgcn_mfma_f32_16x16x32_bf16(ua.s, ub.s, c, 0, 0, 0);
}

// Accumulate the two bf16 halves of u into alo/ahi via v_dot2_f32_bf16.
// Masks (1.0,0.0)/(0.0,1.0) select exactly; products are exact in f32.
__device__ inline void dot2acc2(float& alo, float& ahi, uint u) {
  asm("v_dot2_f32_bf16 %0, %2, %3, %0\n\t"
      "v_dot2_f32_bf16 %1, %2, %4, %1"
      : "+v"(alo), "+v"(ahi)
      : "v"(u), "v"(0x00003F80u), "v"(0x3F800000u));
}

// ---------------------------------------------------------------------------
// x (fp32 [NN][128]) -> xh (bf16 pairs, [NN][64] uints). 8 floats/thread.
// ---------------------------------------------------------------------------
__global__ __launch_bounds__(256) void tobf16_kernel(
    const float* __restrict__ x, uint* __restrict__ xh) {
  int i = blockIdx.x * 256 + threadIdx.x;
  if (i >= NN * 16) return;
  const float4* p = (const float4*)x + (size_t)i * 2;
  float4 a = p[0], b = p[1];
  uint4 o;
  o.x = bf16_2(a.x, a.y);
  o.y = bf16_2(a.z, a.w);
  o.z = bf16_2(b.x, b.y);
  o.w = bf16_2(b.z, b.w);
  ((uint4*)xh)[i] = o;
}

// ---------------------------------------------------------------------------
// Weight prep: w1t[col][k] = bf16([ws1;wn1][k][col]), K=256 -> 128 uints/row.
// ---------------------------------------------------------------------------
__global__ __launch_bounds__(256) void prep_w1_kernel(
    const float* __restrict__ ws1, const float* __restrict__ wn1,
    uint* __restrict__ w1t) {
  int idx = blockIdx.x * 256 + threadIdx.x;   // 128 cols * 128 uints
  if (idx >= 128 * 128) return;
  int col = idx >> 7, ku = idx & 127;
  int k = ku * 2;
  const float* w = (k < 128) ? ws1 : wn1;
  int kk = (k < 128) ? k : (k - 128);
  w1t[idx] = bf16_2(w[(size_t)kk * 128 + col], w[(size_t)(kk + 1) * 128 + col]);
}

// w2t[col][k] = bf16([ws2|wn2][k][col]), cols 0..15 = ws2, 16..31 = wn2, K=128.
__global__ __launch_bounds__(256) void prep_w2_kernel(
    const float* __restrict__ ws2, const float* __restrict__ wn2,
    uint* __restrict__ w2t) {
  int idx = blockIdx.x * 256 + threadIdx.x;   // 32 cols * 64 uints
  if (idx >= 32 * 64) return;
  int col = idx >> 6, ku = idx & 63;
  int k = ku * 2;
  const float* w = (col < 16) ? ws2 : wn2;
  int c = col & 15;
  w2t[idx] = bf16_2(w[(size_t)k * 16 + c], w[(size_t)(k + 1) * 16 + c]);
}

// ---------------------------------------------------------------------------
// Pass A: per-block bucket histogram, LDS atomics only, int4 edge loads.
// ---------------------------------------------------------------------------
__global__ __launch_bounds__(1024) void histA_kernel(
    const int* __restrict__ dst, int* __restrict__ hist2) {
  __shared__ int lh[NBUCK];
  int tid = threadIdx.x;
  int b = blockIdx.x;
  for (int i = tid; i < NBUCK; i += 1024) lh[i] = 0;
  __syncthreads();
  int e0 = b * CHUNK, e1 = min(e0 + CHUNK, NE);
  int ea = (e0 + 3) & ~3;
  int ev = ea + ((e1 - ea) & ~3);
  if (tid < ea - e0) atomicAdd(&lh[dst[e0 + tid] >> 6], 1);
  for (int e = ea + tid * 4; e < ev; e += 4096) {
    int4 d4 = *(const int4*)(dst + e);
    atomicAdd(&lh[d4.x >> 6], 1);
    atomicAdd(&lh[d4.y >> 6], 1);
    atomicAdd(&lh[d4.z >> 6], 1);
    atomicAdd(&lh[d4.w >> 6], 1);
  }
  for (int e = ev + tid; e < e1; e += 1024) atomicAdd(&lh[dst[e] >> 6], 1);
  __syncthreads();
  for (int i = tid; i < NBUCK; i += 1024)
    hist2[(size_t)b * NBUCK + i] = lh[i];
}

// ---------------------------------------------------------------------------
// Transpose hist2[NBLK][NBUCK] -> hist[NBUCK][NBLK].
// ---------------------------------------------------------------------------
__global__ __launch_bounds__(1024) void transpose_kernel(
    const int* __restrict__ hist2, int* __restrict__ hist) {
  __shared__ int t[32][33];
  int tx = threadIdx.x & 31, ty = threadIdx.x >> 5;
  int i = blockIdx.x * 32 + tx;
  int b = blockIdx.y * 32 + ty;
  if (i < NBUCK) t[ty][tx] = hist2[(size_t)b * NBUCK + i];
  __syncthreads();
  int i2 = blockIdx.x * 32 + ty;
  int b2 = blockIdx.y * 32 + tx;
  if (i2 < NBUCK) hist[(size_t)i2 * NBLK + b2] = t[tx][ty];
}

// ---------------------------------------------------------------------------
// Multi-block exclusive scan over hist[NH] (in-place), 3 kernels.
// ---------------------------------------------------------------------------
__global__ __launch_bounds__(1024) void scan_sums_kernel(
    const int* __restrict__ hist, int* __restrict__ sums) {
  __shared__ int sdata[1024];
  int i = blockIdx.x * 1024 + threadIdx.x;
  sdata[threadIdx.x] = (i < NH) ? hist[i] : 0;
  __syncthreads();
#pragma unroll
  for (int s = 512; s > 0; s >>= 1) {
    if (threadIdx.x < s) sdata[threadIdx.x] += sdata[threadIdx.x + s];
    __syncthreads();
  }
  if (threadIdx.x == 0) sums[blockIdx.x] = sdata[0];
}

__global__ __launch_bounds__(512) void scan_tops_kernel(int* __restrict__ sums) {
  __shared__ int buf[2][512];
  int tid = threadIdx.x;
  int v = (tid < NSB) ? sums[tid] : 0;
  buf[0][tid] = v;
  __syncthreads();
  int pp = 0;
#pragma unroll
  for (int d = 1; d < 512; d <<= 1) {
    buf[pp ^ 1][tid] = buf[pp][tid] + ((tid >= d) ? buf[pp][tid - d] : 0);
    pp ^= 1;
    __syncthreads();
  }
  if (tid < NSB) sums[tid] = buf[pp][tid] - v;  // exclusive
}

__global__ __launch_bounds__(1024) void scan_apply_kernel(
    int* __restrict__ hist, const int* __restrict__ sums) {
  __shared__ int buf[2][1024];
  int tid = threadIdx.x;
  int i = blockIdx.x * 1024 + tid;
  int v = (i < NH) ? hist[i] : 0;
  buf[0][tid] = v;
  __syncthreads();
  int pp = 0;
#pragma unroll
  for (int d = 1; d < 1024; d <<= 1) {
    buf[pp ^ 1][tid] = buf[pp][tid] + ((tid >= d) ? buf[pp][tid - d] : 0);
    pp ^= 1;
    __syncthreads();
  }
  if (i < NH) hist[i] = sums[blockIdx.x] + buf[pp][tid] - v;  // exclusive
}

// ---------------------------------------------------------------------------
// Pass C: contention-free scatter, int4 edge loads.
// ---------------------------------------------------------------------------
__global__ __launch_bounds__(1024) void scatter3_kernel(
    const int* __restrict__ src, const int* __restrict__ dst,
    const int* __restrict__ scanned, unsigned int* __restrict__ ebuf) {
  __shared__ int cur[NBUCK];
  int tid = threadIdx.x;
  int b = blockIdx.x;
  for (int i = tid; i < NBUCK; i += 1024) cur[i] = scanned[i * NBLK + b];
  __syncthreads();
  int e0 = b * CHUNK, e1 = min(e0 + CHUNK, NE);
  int ea = (e0 + 3) & ~3;
  int ev = ea + ((e1 - ea) & ~3);
  if (tid < ea - e0) {
    int e = e0 + tid;
    int d = dst[e];
    int p = atomicAdd(&cur[d >> 6], 1);
    ebuf[p] = ((unsigned int)(d & 63) << 17) | (unsigned int)src[e];
  }
  for (int e = ea + tid * 4; e < ev; e += 4096) {
    int4 d4 = *(const int4*)(dst + e);
    int4 s4 = *(const int4*)(src + e);
    int p0 = atomicAdd(&cur[d4.x >> 6], 1);
    ebuf[p0] = ((unsigned int)(d4.x & 63) << 17) | (unsigned int)s4.x;
    int p1 = atomicAdd(&cur[d4.y >> 6], 1);
    ebuf[p1] = ((unsigned int)(d4.y & 63) << 17) | (unsigned int)s4.y;
    int p2 = atomicAdd(&cur[d4.z >> 6], 1);
    ebuf[p2] = ((unsigned int)(d4.z & 63) << 17) | (unsigned int)s4.z;
    int p3 = atomicAdd(&cur[d4.w >> 6], 1);
    ebuf[p3] = ((unsigned int)(d4.w & 63) << 17) | (unsigned int)s4.w;
  }
  for (int e = ev + tid; e < e1; e += 1024) {
    int d = dst[e];
    int p = atomicAdd(&cur[d >> 6], 1);
    ebuf[p] = ((unsigned int)(d & 63) << 17) | (unsigned int)src[e];
  }
}

// ---------------------------------------------------------------------------
// Per-bucket counting sort, two-pass (computes deg + off, no global atomics).
// ---------------------------------------------------------------------------
__global__ __launch_bounds__(256) void bucket_sort_kernel(
    const unsigned int* __restrict__ ebuf, const int* __restrict__ scanned,
    int* __restrict__ deg, int* __restrict__ off, int* __restrict__ perm) {
  __shared__ int cnt[BSZ];
  __shared__ int loc_off[BSZ];
  int tid = threadIdx.x;
  int b = blockIdx.x;
  int e0 = scanned[b * NBLK];
  int e1 = (b + 1 < NBUCK) ? scanned[(b + 1) * NBLK] : NE;

  if (tid < BSZ) cnt[tid] = 0;
  __syncthreads();
  for (int e = e0 + tid; e < e1; e += 256)
    atomicAdd(&cnt[ebuf[e] >> 17], 1);
  __syncthreads();

  if (tid < BSZ) {   // threads 0..63 = one wave
    int v = cnt[tid];
    int incl = v;
#pragma unroll
    for (int d = 1; d < 64; d <<= 1) {
      int t = __shfl_up(incl, d);
      if (tid >= d) incl += t;
    }
    int excl = incl - v;
    loc_off[tid] = e0 + excl;
    int node = b * BSZ + tid;
    if (node < NN) { off[node] = e0 + excl; deg[node] = v; }
    cnt[tid] = 0;
  }
  __syncthreads();

  for (int e = e0 + tid; e < e1; e += 256) {
    unsigned int pk = ebuf[e];
    int dl = pk >> 17;
    int p = loc_off[dl] + atomicAdd(&cnt[dl], 1);
    perm[p] = (int)(pk & 0x1FFFF);
  }
}

// ---------------------------------------------------------------------------
// Layer-1 mean aggregation: wave per node, 4 edges x 16 lanes, 4 gathers in
// flight (2 accumulator sets), v_dot2_f32_bf16 accumulate (exact).
// ---------------------------------------------------------------------------
__global__ __launch_bounds__(256) void mean1_kernel(
    const uint* __restrict__ xh, const int* __restrict__ off,
    const int* __restrict__ deg, const int* __restrict__ perm,
    uint* __restrict__ mean1h) {
  int node = blockIdx.x * 4 + (threadIdx.x >> 6);
  int lane = threadIdx.x & 63;
  if (node >= NN) return;
  int o = off[node], dg = deg[node];
  int sub = lane >> 4;   // 4 edge slots
  int q = lane & 15;     // which uint4 (8 bf16) of the 64-uint row
  float A0=0,A1=0,A2=0,A3=0,A4=0,A5=0,A6=0,A7=0;
  float B0=0,B1=0,B2=0,B3=0,B4=0,B5=0,B6=0,B7=0;
  int j = sub;
  for (; j + 12 < dg; j += 16) {   // 4 gathers in flight
    int s0 = perm[o + j];
    int s1 = perm[o + j + 4];
    int s2 = perm[o + j + 8];
    int s3 = perm[o + j + 12];
    uint4 v0 = *(const uint4*)(xh + (size_t)s0 * 64 + q * 4);
    uint4 v1 = *(const uint4*)(xh + (size_t)s1 * 64 + q * 4);
    uint4 v2 = *(const uint4*)(xh + (size_t)s2 * 64 + q * 4);
    uint4 v3 = *(const uint4*)(xh + (size_t)s3 * 64 + q * 4);
    dot2acc2(A0,A1,v0.x); dot2acc2(A2,A3,v0.y); dot2acc2(A4,A5,v0.z); dot2acc2(A6,A7,v0.w);
    dot2acc2(B0,B1,v1.x); dot2acc2(B2,B3,v1.y); dot2acc2(B4,B5,v1.z); dot2acc2(B6,B7,v1.w);
    dot2acc2(A0,A1,v2.x); dot2acc2(A2,A3,v2.y); dot2acc2(A4,A5,v2.z); dot2acc2(A6,A7,v2.w);
    dot2acc2(B0,B1,v3.x); dot2acc2(B2,B3,v3.y); dot2acc2(B4,B5,v3.z); dot2acc2(B6,B7,v3.w);
  }
  for (; j < dg; j += 4) {
    int s0 = perm[o + j];
    uint4 v0 = *(const uint4*)(xh + (size_t)s0 * 64 + q * 4);
    dot2acc2(A0,A1,v0.x); dot2acc2(A2,A3,v0.y); dot2acc2(A4,A5,v0.z); dot2acc2(A6,A7,v0.w);
  }
  A0+=B0; A1+=B1; A2+=B2; A3+=B3; A4+=B4; A5+=B5; A6+=B6; A7+=B7;
#pragma unroll
  for (int d = 16; d <= 32; d <<= 1) {
    A0 += __shfl_xor(A0, d); A1 += __shfl_xor(A1, d);
    A2 += __shfl_xor(A2, d); A3 += __shfl_xor(A3, d);
    A4 += __shfl_xor(A4, d); A5 += __shfl_xor(A5, d);
    A6 += __shfl_xor(A6, d); A7 += __shfl_xor(A7, d);
  }
  if (sub == 0) {
    float rd = 1.0f / fmaxf((float)dg, 1.0f);
    uint4 o4;
    o4.x = bf16_2(A0 * rd, A1 * rd);
    o4.y = bf16_2(A2 * rd, A3 * rd);
    o4.z = bf16_2(A4 * rd, A5 * rd);
    o4.w = bf16_2(A6 * rd, A7 * rd);
    *(uint4*)(mean1h + (size_t)node * 64 + q * 4) = o4;
  }
}

// ---------------------------------------------------------------------------
// GEMM1 (MFMA bf16, LDS-staged B): h = relu([xh | mean1h] @ w1t^T + b1).
// ---------------------------------------------------------------------------
__global__ __launch_bounds__(256) void gemm1_mfma_kernel(
    const uint* __restrict__ xh, const uint* __restrict__ m1h,
    const uint* __restrict__ w1t, const float* __restrict__ b1,
    ushort_t* __restrict__ hout) {
  __shared__ uint lds_w[128 * 128];   // 64 KB
  int tid = threadIdx.x;

#pragma unroll
  for (int i = 0; i < 16; i++) {
    int g = tid + i * 256;
    int row = g >> 5, c = g & 31;
    uint4 v = ((const uint4*)w1t)[g];
    int cs = c ^ (row & 7);
    *(uint4*)&lds_w[row * 128 + cs * 4] = v;
  }
  __syncthreads();

  int wv = tid >> 6;
  int lane = tid & 63;
  int lr = lane & 15, lk = lane >> 4;
  int r0 = blockIdx.x * 256 + wv * 64;
  if (r0 >= NN) return;   // after the only barrier

  f32x4 acc[4][8];
#pragma unroll
  for (int i = 0; i < 4; i++)
#pragma unroll
    for (int j = 0; j < 8; j++) acc[i][j] = (f32x4){0.f, 0.f, 0.f, 0.f};

#pragma unroll
  for (int ks = 0; ks < 8; ks++) {
    const uint* A = (ks < 4) ? xh : m1h;
    int ku = (ks & 3) * 16 + lk * 4;
    uint4 a[4];
#pragma unroll
    for (int rt = 0; rt < 4; rt++) {
      int row = r0 + rt * 16 + lr;
      if (row >= NN) row = NN - 1;
      a[rt] = *(const uint4*)(A + (size_t)row * 64 + ku);
    }
    int cbase = ks * 4 + lk;
#pragma unroll
    for (int ct = 0; ct < 8; ct++) {
      int brow = ct * 16 + lr;
      int cs = cbase ^ (lr & 7);
      uint4 bu = *(const uint4*)&lds_w[brow * 128 + cs * 4];
#pragma unroll
      for (int rt = 0; rt < 4; rt++)
        acc[rt][ct] = mfma_bf16(a[rt], bu, acc[rt][ct]);
    }
  }

  float bias[8];
#pragma unroll
  for (int ct = 0; ct < 8; ct++) bias[ct] = b1[ct * 16 + lr];

#pragma unroll
  for (int rt = 0; rt < 4; rt++) {
#pragma unroll
    for (int r = 0; r < 4; r++) {
      int row = r0 + rt * 16 + lk * 4 + r;
      if (row < NN) {
#pragma unroll
        for (int ct = 0; ct < 8; ct++) {
          int col = ct * 16 + lr;
          float v = fmaxf(acc[rt][ct][r] + bias[ct], 0.0f);
          hout[(size_t)row * 128 + col] = (ushort_t)bf16_1(v);
        }
      }
    }
  }
}

// ---------------------------------------------------------------------------
// GEMM2 (MFMA bf16): oself (fp32) and h2 (bf16) = h @ w2t^T. K=128, N=32.
// ---------------------------------------------------------------------------
__global__ __launch_bounds__(256) void gemm2_mfma_kernel(
    const uint* __restrict__ h, const uint* __restrict__ w2t,
    float* __restrict__ oself, ushort_t* __restrict__ h2b) {
  int wid = (blockIdx.x * 256 + threadIdx.x) >> 6;
  int lane = threadIdx.x & 63;
  int r0 = wid * 32;
  if (r0 >= NN) return;
  int lr = lane & 15, lk = lane >> 4;

  f32x4 acc[2][2];
#pragma unroll
  for (int i = 0; i < 2; i++)
#pragma unroll
    for (int j = 0; j < 2; j++) acc[i][j] = (f32x4){0.f, 0.f, 0.f, 0.f};

#pragma unroll
  for (int ks = 0; ks < 4; ks++) {
    int ku = ks * 16;
    uint4 a0 = *(const uint4*)(h + (size_t)(r0 + lr) * 64 + ku + lk * 4);
    uint4 a1 = *(const uint4*)(h + (size_t)(r0 + 16 + lr) * 64 + ku + lk * 4);
#pragma unroll
    for (int ct = 0; ct < 2; ct++) {
      uint4 bu = *(const uint4*)(w2t + (size_t)(ct * 16 + lr) * 64 + ku + lk * 4);
      acc[0][ct] = mfma_bf16(a0, bu, acc[0][ct]);
      acc[1][ct] = mfma_bf16(a1, bu, acc[1][ct]);
    }
  }

#pragma unroll
  for (int rt = 0; rt < 2; rt++) {
#pragma unroll
    for (int r = 0; r < 4; r++) {
      int row = r0 + rt * 16 + lk * 4 + r;
      oself[(size_t)row * 16 + lr] = acc[rt][0][r];
      h2b[(size_t)row * 16 + lr]  = (ushort_t)bf16_1(acc[rt][1][r]);
    }
  }
}

// ---------------------------------------------------------------------------
// Layer-2 mean aggregation from bf16 rows (32B): wave per node,
// 32 edges in parallel x 2 lanes/edge (uint4 = 8 feats each), dot2 accum.
// ---------------------------------------------------------------------------
__global__ __launch_bounds__(256) void mean2_kernel(
    const ushort_t* __restrict__ h2b, const int* __restrict__ off,
    const int* __restrict__ deg, const int* __restrict__ perm,
    float* __restrict__ mean2) {
  int node = blockIdx.x * 4 + (threadIdx.x >> 6);
  int lane = threadIdx.x & 63;
  if (node >= NN) return;
  int o = off[node], dg = deg[node];
  int sub = lane >> 1;   // 32 edge slots
  int q = lane & 1;      // which uint4 half (8 feats)
  float a0=0,a1=0,a2=0,a3=0,a4=0,a5=0,a6=0,a7=0;
  for (int j = sub; j < dg; j += 32) {
    int s = perm[o + j];
    uint4 v = *(const uint4*)((const uint*)h2b + (size_t)s * 8 + q * 4);
    dot2acc2(a0,a1,v.x); dot2acc2(a2,a3,v.y);
    dot2acc2(a4,a5,v.z); dot2acc2(a6,a7,v.w);
  }
#pragma unroll
  for (int d = 2; d <= 32; d <<= 1) {
    a0 += __shfl_xor(a0, d); a1 += __shfl_xor(a1, d);
    a2 += __shfl_xor(a2, d); a3 += __shfl_xor(a3, d);
    a4 += __shfl_xor(a4, d); a5 += __shfl_xor(a5, d);
    a6 += __shfl_xor(a6, d); a7 += __shfl_xor(a7, d);
  }
  if (sub == 0) {
    float rd = 1.0f / fmaxf((float)dg, 1.0f);
    float* pm = mean2 + (size_t)node * 16 + q * 8;
    float4 r0, r1;
    r0.x = a0 * rd; r0.y = a1 * rd; r0.z = a2 * rd; r0.w = a3 * rd;
    r1.x = a4 * rd; r1.y = a5 * rd; r1.z = a6 * rd; r1.w = a7 * rd;
    *(float4*)pm = r0;
    *(float4*)(pm + 4) = r1;
  }
}

// ---------------------------------------------------------------------------
// Final: logits = oself + b2 + mean2; out = log_softmax(logits).
// ---------------------------------------------------------------------------
__global__ __launch_bounds__(256) void final_kernel(
    const float* __restrict__ oself, const float* __restrict__ mean2,
    const float* __restrict__ b2, float* __restrict__ out) {
  int i = blockIdx.x * 256 + threadIdx.x;
  if (i >= NN) return;
  float l[16];
  const float4* po = (const float4*)(oself + (size_t)i * 16);
  const float4* pa = (const float4*)(mean2 + (size_t)i * 16);
#pragma unroll
  for (int q = 0; q < 4; q++) {
    float4 o = po[q], a = pa[q];
    l[q * 4 + 0] = o.x + b2[q * 4 + 0] + a.x;
    l[q * 4 + 1] = o.y + b2[q * 4 + 1] + a.y;
    l[q * 4 + 2] = o.z + b2[q * 4 + 2] + a.z;
    l[q * 4 + 3] = o.w + b2[q * 4 + 3] + a.w;
  }
  float m = l[0];
#pragma unroll
  for (int c = 1; c < 16; c++) m = fmaxf(m, l[c]);
  float s = 0.0f;
#pragma unroll
  for (int c = 0; c < 16; c++) s += expf(l[c] - m);
  float ls = logf(s);
  float4* po2 = (float4*)(out + (size_t)i * 16);
#pragma unroll
  for (int q = 0; q < 4; q++) {
    float4 v;
    v.x = l[q * 4 + 0] - m - ls;
    v.y = l[q * 4 + 1] - m - ls;
    v.z = l[q * 4 + 2] - m - ls;
    v.w = l[q * 4 + 3] - m - ls;
    po2[q] = v;
  }
}

// ---------------------------------------------------------------------------
extern "C" void kernel_launch(void* const* d_in, const int* in_sizes, int n_in,
                              void* d_out, int out_size, void* d_ws, size_t ws_size,
                              hipStream_t stream) {
  const float* x   = (const float*)d_in[0];
  const int*   src = (const int*)d_in[1];
  const int*   dst = (const int*)d_in[2];
  const float* ws1 = (const float*)d_in[3];
  const float* wn1 = (const float*)d_in[4];
  const float* b1  = (const float*)d_in[5];
  const float* ws2 = (const float*)d_in[6];
  const float* wn2 = (const float*)d_in[7];
  const float* b2  = (const float*)d_in[8];
  float* out = (float*)d_out;

  // workspace layout
  char* p = (char*)d_ws;
  int* deg   = (int*)p;  p += (size_t)NN * 4;
  int* off   = (int*)p;  p += (size_t)NN * 4;
  int* hist  = (int*)p;  p += (size_t)NH * 4;            // bucket-major, scanned in place
  int* hist2 = (int*)p;  p += (size_t)NH * 4;            // block-major
  int* sums  = (int*)p;  p += (size_t)((NSB + 31) & ~31) * 4;
  unsigned int* ebuf = (unsigned int*)p; p += (size_t)NE * 4;
  int* perm = (int*)p;  p += (size_t)NE * 4;
  uint* xh   = (uint*)p; p += (size_t)NN * 64 * 4;       // bf16 x
  uint* m1h  = (uint*)p; p += (size_t)NN * 64 * 4;       // bf16 mean1
  uint* hbuf = (uint*)p; p += (size_t)NN * 64 * 4;       // bf16 h
  uint* w1t  = (uint*)p; p += (size_t)128 * 128 * 4;     // bf16 [ws1;wn1]^T
  uint* w2t  = (uint*)p; p += (size_t)32 * 64 * 4;       // bf16 [ws2|wn2]^T
  ushort_t* h2b = (ushort_t*)p; p += (size_t)NN * 16 * 2; // bf16 h2
  float* osf   = (float*)p; p += (size_t)NN * 16 * 4;
  float* mean2 = (float*)p; p += (size_t)NN * 16 * 4;

  tobf16_kernel<<<(NN * 16 + 255) / 256, 256, 0, stream>>>(x, xh);
  prep_w1_kernel<<<(128 * 128 + 255) / 256, 256, 0, stream>>>(ws1, wn1, w1t);
  prep_w2_kernel<<<(32 * 64 + 255) / 256, 256, 0, stream>>>(ws2, wn2, w2t);

  histA_kernel<<<NBLK, 1024, 0, stream>>>(dst, hist2);
  transpose_kernel<<<dim3((NBUCK + 31) / 32, NBLK / 32), 1024, 0, stream>>>(
      hist2, hist);
  scan_sums_kernel<<<NSB, 1024, 0, stream>>>(hist, sums);
  scan_tops_kernel<<<1, 512, 0, stream>>>(sums);
  scan_apply_kernel<<<NSB, 1024, 0, stream>>>(hist, sums);
  scatter3_kernel<<<NBLK, 1024, 0, stream>>>(src, dst, hist, ebuf);
  bucket_sort_kernel<<<NBUCK, 256, 0, stream>>>(ebuf, hist, deg, off, perm);

  mean1_kernel<<<(NN + 3) / 4, 256, 0, stream>>>(xh, off, deg, perm, m1h);

  gemm1_mfma_kernel<<<(NN + 255) / 256, 256, 0, stream>>>(
      xh, m1h, w1t, b1, (ushort_t*)hbuf);
  gemm2_mfma_kernel<<<(NN + 127) / 128, 256, 0, stream>>>(hbuf, w2t, osf, h2b);

  mean2_kernel<<<(NN + 3) / 4, 256, 0, stream>>>(h2b, off, deg, perm, mean2);
  final_kernel<<<(NN + 255) / 256, 256, 0, stream>>>(osf, mean2, b2, out);
}